// Round 2
// baseline (138.948 us; speedup 1.0000x reference)
//
#include <hip/hip_runtime.h>
#include <math.h>

#define BB 8
#define NCC 1024
#define NTT 1024
#define HH 128
#define DYY 32
#define NTB 16                   // targets per block: 512 blocks, 2 blocks/CU
#define LOG2E 1.44269504088896340736f

// LDS arena: 4400 floats = 17.6 KB. De-staged design: only data that is
// genuinely cross-wave-shared lives in LDS (h matrix, L3 partials, sigl,
// epilogue combine). W and yc are read straight from L2 (FETCH_SIZE showed
// the whole problem is cache-resident; staging them was pure overhead and
// forced ~52 barriers/block; now ~6).
//   phase 1:  hbuf[HB, 16x132=2112) red[RED,+1536=3648)
//   epilogue: cmb[CMB,4224) sl[SL,+128=4352)   (aliases hbuf/red, both dead)
//   sigl[SIGL,+48=4400)  -- does NOT alias cmb/sl, so no extra fence between
//                           late sigl readers and early combine depositors
#define HB 0
#define RED 2112
#define CMB 0
#define SL 4224
#define SIGL 4352
#define SMEM_SZ 4400
#define HSTRIDE 132              // mult of 4: aligned ds_read_b128 on h rows;
                                 // bank=(4p+k)%32: p,p+8 alias = 2-way = free

// 512 blocks x 512 threads.
// Phase 1 MLP: thread=(jg 0..31, p 0..15), 4 cols. W1/W2 read DIRECTLY from
// global: thread (jg,p) reads W[k][4jg..4jg+3]; the 16 lanes sharing jg
// broadcast, and a wave's 4 jg groups form one contiguous 64B segment per
// k-row -> perfectly coalesced L2 stream, no LDS, no per-chunk barriers.
// Phase 2 attn: wave w owns contexts [w*128,(w+1)*128) exclusively -> no
// cross-wave sharing -> barrier-free. lane=(ns,dg,tl): ns halves the n-range,
// dg halves d. P<=0 (sig>0) => exp(P)<=1: no max subtraction needed.
// Epilogue: shfl_xor(32) merges ns pairs in-register, 8-slot LDS combine.
__global__ __launch_bounds__(512) void k_fused(const float* __restrict__ xc,
                                               const float* __restrict__ yc,
                                               const float* __restrict__ xt,
                                               const float* __restrict__ W0,
                                               const float* __restrict__ b0,
                                               const float* __restrict__ W1,
                                               const float* __restrict__ b1,
                                               const float* __restrict__ W2,
                                               const float* __restrict__ b2,
                                               const float* __restrict__ W3,
                                               const float* __restrict__ b3,
                                               float* __restrict__ out) {
    const int tid = threadIdx.x;
    const int t0 = blockIdx.x * NTB;     // global target base (xt/out flat B*Nt)
    const int b = blockIdx.x >> 6;       // 64 blocks per batch

    __shared__ float smem[SMEM_SZ];      // 17.6 KB

    // ================= phase 1: MLP =================
    {
        const int jg = tid >> 4;         // 0..31 col-group (4 cols)
        const int p = tid & 15;          // 0..15 point
        const int j0 = jg * 4;

        // ---- L0 (W0 columns as float4, 16-lane broadcast) ----
        const float* xr = xt + (size_t)(t0 + p) * 3;
        const float x0 = xr[0], x1 = xr[1], x2 = xr[2];
        const float4* W0v = (const float4*)W0;
        const float4 w0a = W0v[0 * 32 + jg];
        const float4 w0b = W0v[1 * 32 + jg];
        const float4 w0c = W0v[2 * 32 + jg];
        const float4 bb0 = ((const float4*)b0)[jg];
        float4 h0;
        h0.x = fmaxf(fmaf(x0, w0a.x, fmaf(x1, w0b.x, fmaf(x2, w0c.x, bb0.x))), 0.f);
        h0.y = fmaxf(fmaf(x0, w0a.y, fmaf(x1, w0b.y, fmaf(x2, w0c.y, bb0.y))), 0.f);
        h0.z = fmaxf(fmaf(x0, w0a.z, fmaf(x1, w0b.z, fmaf(x2, w0c.z, bb0.z))), 0.f);
        h0.w = fmaxf(fmaf(x0, w0a.w, fmaf(x1, w0b.w, fmaf(x2, w0c.w, bb0.w))), 0.f);
        *(float4*)(smem + HB + p * HSTRIDE + j0) = h0;
        __syncthreads();

        // ---- L1, L2: W streamed straight from L2, h from LDS (b128) ----
        float o[4];
        const float* hrow = smem + HB + p * HSTRIDE;
        for (int l = 0; l < 2; ++l) {
            const float4* __restrict__ Wv = (const float4*)((l == 0) ? W1 : W2);
            const float4 bi = ((const float4*)((l == 0) ? b1 : b2))[jg];
            float a0 = bi.x, a1 = bi.y, a2 = bi.z, a3 = bi.w;
#pragma unroll 4
            for (int k4 = 0; k4 < 32; ++k4) {
                const float4 ch = *(const float4*)(hrow + k4 * 4);
                const float4 wk0 = Wv[(k4 * 4 + 0) * 32 + jg];
                const float4 wk1 = Wv[(k4 * 4 + 1) * 32 + jg];
                const float4 wk2 = Wv[(k4 * 4 + 2) * 32 + jg];
                const float4 wk3 = Wv[(k4 * 4 + 3) * 32 + jg];
                a0 = fmaf(ch.x, wk0.x, a0);
                a1 = fmaf(ch.x, wk0.y, a1);
                a2 = fmaf(ch.x, wk0.z, a2);
                a3 = fmaf(ch.x, wk0.w, a3);
                a0 = fmaf(ch.y, wk1.x, a0);
                a1 = fmaf(ch.y, wk1.y, a1);
                a2 = fmaf(ch.y, wk1.z, a2);
                a3 = fmaf(ch.y, wk1.w, a3);
                a0 = fmaf(ch.z, wk2.x, a0);
                a1 = fmaf(ch.z, wk2.y, a1);
                a2 = fmaf(ch.z, wk2.z, a2);
                a3 = fmaf(ch.z, wk2.w, a3);
                a0 = fmaf(ch.w, wk3.x, a0);
                a1 = fmaf(ch.w, wk3.y, a1);
                a2 = fmaf(ch.w, wk3.z, a2);
                a3 = fmaf(ch.w, wk3.w, a3);
            }
            o[0] = fmaxf(a0, 0.f);
            o[1] = fmaxf(a1, 0.f);
            o[2] = fmaxf(a2, 0.f);
            o[3] = fmaxf(a3, 0.f);
            if (l == 0) {
                __syncthreads();          // old-h reads done
                float4 hn;
                hn.x = o[0]; hn.y = o[1]; hn.z = o[2]; hn.w = o[3];
                *(float4*)(smem + HB + p * HSTRIDE + j0) = hn;
                __syncthreads();          // new h visible
            }
        }

        // ---- L3 + exp -> sig*log2e in LDS ----
        // W3 rows j0..j0+3 (3 floats each) = 12 contiguous floats = 3 float4
        const float4* W3v = (const float4*)W3;
        const float4 wr0 = W3v[jg * 3 + 0];
        const float4 wr1 = W3v[jg * 3 + 1];
        const float4 wr2 = W3v[jg * 3 + 2];
        float p0 = o[0] * wr0.x + o[1] * wr0.w + o[2] * wr1.z + o[3] * wr2.y;
        float p1 = o[0] * wr0.y + o[1] * wr1.x + o[2] * wr1.w + o[3] * wr2.z;
        float p2 = o[0] * wr0.z + o[1] * wr1.y + o[2] * wr2.x + o[3] * wr2.w;
        smem[RED + (jg * 16 + p) * 3 + 0] = p0;
        smem[RED + (jg * 16 + p) * 3 + 1] = p1;
        smem[RED + (jg * 16 + p) * 3 + 2] = p2;
        __syncthreads();
        if (tid < 48) {
            int r = tid / 3, cidx = tid - r * 3;
            float v = b3[cidx];
#pragma unroll
            for (int g = 0; g < 32; ++g) v += smem[RED + (g * 16 + r) * 3 + cidx];
            smem[SIGL + r * 3 + cidx] = __expf(v) * LOG2E;
        }
        __syncthreads();                  // sigl ready
    }

    // ========== phase 2: attention, barrier-free, direct from L2 ==========
    const int w = tid >> 6;          // 0..7 wave: owns n in [w*128,(w+1)*128)
    const int lane = tid & 63;
    const int tl = lane & 15;        // target within block
    const int dg = (lane >> 4) & 1;  // d-half (16 floats)
    const int ns = lane >> 5;        // n sub-half (64 contexts each)

    const float s0 = smem[SIGL + tl * 3 + 0];
    const float s1 = smem[SIGL + tl * 3 + 1];
    const float s2 = smem[SIGL + tl * 3 + 2];
    const float* ar = xt + (size_t)(t0 + tl) * 3;
    const float a0 = ar[0], a1 = ar[1], a2 = ar[2];

    const int nbase = w * 128 + ns * 64;
    const float* __restrict__ xrow = xc + (size_t)b * NCC * 3 + (size_t)nbase * 3;
    const float4* __restrict__ yrow =
        (const float4*)(yc + (size_t)b * NCC * DYY) + (size_t)nbase * 8 + dg * 4;

    float acc[16];
#pragma unroll
    for (int i = 0; i < 16; ++i) acc[i] = 0.f;
    float l = 0.f;

#pragma unroll 4
    for (int s = 0; s < 64; ++s) {
        const float d0 = xrow[s * 3 + 0] - a0;
        const float d1 = xrow[s * 3 + 1] - a1;
        const float d2 = xrow[s * 3 + 2] - a2;
        const float pp = fmaf(s0, d0 * d0, fmaf(s1, d1 * d1, s2 * (d2 * d2)));
        const float e = exp2f(-pp);
        l += e;
        const float4* yv = yrow + (size_t)s * 8;
        const float4 q0 = yv[0], q1 = yv[1], q2 = yv[2], q3 = yv[3];
        acc[0]  = fmaf(e, q0.x, acc[0]);
        acc[1]  = fmaf(e, q0.y, acc[1]);
        acc[2]  = fmaf(e, q0.z, acc[2]);
        acc[3]  = fmaf(e, q0.w, acc[3]);
        acc[4]  = fmaf(e, q1.x, acc[4]);
        acc[5]  = fmaf(e, q1.y, acc[5]);
        acc[6]  = fmaf(e, q1.z, acc[6]);
        acc[7]  = fmaf(e, q1.w, acc[7]);
        acc[8]  = fmaf(e, q2.x, acc[8]);
        acc[9]  = fmaf(e, q2.y, acc[9]);
        acc[10] = fmaf(e, q2.z, acc[10]);
        acc[11] = fmaf(e, q2.w, acc[11]);
        acc[12] = fmaf(e, q3.x, acc[12]);
        acc[13] = fmaf(e, q3.y, acc[13]);
        acc[14] = fmaf(e, q3.z, acc[14]);
        acc[15] = fmaf(e, q3.w, acc[15]);
    }

    // ---- merge ns pairs in-register, 8-slot LDS combine, write ----
#pragma unroll
    for (int i = 0; i < 16; ++i) acc[i] += __shfl_xor(acc[i], 32, 64);
    l += __shfl_xor(l, 32, 64);

    if (ns == 0) {
#pragma unroll
        for (int i = 0; i < 16; ++i)
            smem[CMB + (w * 16 + tl) * 33 + dg * 16 + i] = acc[i];
        if (dg == 0) smem[SL + w * 16 + tl] = l;
    }
    __syncthreads();
    {
        const int rtl = tid >> 5, d = tid & 31;   // each thread owns one output
        float ssum = 0.f, lsum = 0.f;
#pragma unroll
        for (int ww = 0; ww < 8; ++ww) {
            ssum += smem[CMB + (ww * 16 + rtl) * 33 + d];
            lsum += smem[SL + ww * 16 + rtl];
        }
        out[(size_t)(t0 + rtl) * DYY + d] = ssum / lsum;
    }
}

extern "C" void kernel_launch(void* const* d_in, const int* in_sizes, int n_in,
                              void* d_out, int out_size, void* d_ws, size_t ws_size,
                              hipStream_t stream) {
    const float* xc = (const float*)d_in[0];
    const float* yc = (const float*)d_in[1];
    const float* xt = (const float*)d_in[2];
    const float* W0 = (const float*)d_in[3];
    const float* b0 = (const float*)d_in[4];
    const float* W1 = (const float*)d_in[5];
    const float* b1 = (const float*)d_in[6];
    const float* W2 = (const float*)d_in[7];
    const float* b2 = (const float*)d_in[8];
    const float* W3 = (const float*)d_in[9];
    const float* b3 = (const float*)d_in[10];
    float* out = (float*)d_out;

    k_fused<<<dim3(BB * NTT / NTB), dim3(512), 0, stream>>>(xc, yc, xt, W0, b0,
                                                            W1, b1, W2, b2, W3,
                                                            b3, out);
}